// Round 4
// baseline (442.761 us; speedup 1.0000x reference)
//
#include <hip/hip_runtime.h>

#define N_NODES 100000
#define N_EDGES 3200000
#define F_IN 128
#define F_HID 16

#define BK_LG 8
#define BK_NODES 256                                  // nodes per bucket
#define NB ((N_NODES + BK_NODES - 1) / BK_NODES)      // 391 buckets
#define NB_P 512                                      // padded scan width (== BIN_T)
#define BCAP 9216                                     // edges/bucket cap (avg 8186, +11 sigma)
#define CHUNK 4096                                    // edges per bin block
#define BIN_T 512
#define EPT (CHUNK / BIN_T)                           // 8 edges/thread
#define CUR_STRIDE 16                                 // gcursor striped: 1 counter / 64B line

// ---------------------------------------------------------------------------
// K1: z0 = x @ W0
// ---------------------------------------------------------------------------
__global__ __launch_bounds__(256) void k_xw0(const float* __restrict__ x,
                                             const float* __restrict__ W0,
                                             float* __restrict__ z0, int n) {
    __shared__ float xs[64][F_IN + 1];
    __shared__ float w0s[F_IN * F_HID];
    const int tid = threadIdx.x;
    for (int i = tid; i < F_IN * F_HID; i += 256) w0s[i] = W0[i];
    const int row0 = blockIdx.x * 64;
    for (int i = tid; i < 64 * (F_IN / 4); i += 256) {
        int r  = i / (F_IN / 4);
        int c4 = i % (F_IN / 4);
        float4 v = make_float4(0.f, 0.f, 0.f, 0.f);
        int row = row0 + r;
        if (row < n) v = ((const float4*)(x + (size_t)row * F_IN))[c4];
        xs[r][c4 * 4 + 0] = v.x; xs[r][c4 * 4 + 1] = v.y;
        xs[r][c4 * 4 + 2] = v.z; xs[r][c4 * 4 + 3] = v.w;
    }
    __syncthreads();
    const int r  = tid & 63;
    const int cg = tid >> 6;
    float a0 = 0.f, a1 = 0.f, a2 = 0.f, a3 = 0.f;
    #pragma unroll 8
    for (int k = 0; k < F_IN; ++k) {
        float xv = xs[r][k];
        a0 = fmaf(xv, w0s[k * F_HID + cg * 4 + 0], a0);
        a1 = fmaf(xv, w0s[k * F_HID + cg * 4 + 1], a1);
        a2 = fmaf(xv, w0s[k * F_HID + cg * 4 + 2], a2);
        a3 = fmaf(xv, w0s[k * F_HID + cg * 4 + 3], a3);
    }
    int row = row0 + r;
    if (row < n) {
        ((float4*)(z0 + (size_t)row * F_HID))[cg] = make_float4(a0, a1, a2, a3);
    }
}

// ---------------------------------------------------------------------------
// K2: bin edges by dst-bucket. Per block: LDS count -> LDS scan -> ~NB global
// atomics (striped lines) -> LDS-staged grouped placement -> coalesced flush.
// Packed edge: .x = w bits, .y = src | (dst_local << 17).
// ---------------------------------------------------------------------------
__global__ __launch_bounds__(BIN_T) void k_bin(const int* __restrict__ src,
                                               const int* __restrict__ dst,
                                               const float* __restrict__ ew,
                                               int* __restrict__ gcursor,
                                               int2* __restrict__ ebin) {
    __shared__ int cnt[NB_P], scn[NB_P], run[NB_P], gb[NB_P], alw[NB_P];
    __shared__ int2 stage[CHUNK];
    __shared__ unsigned short sbid[CHUNK];
    const int tid = threadIdx.x;
    const int e0  = blockIdx.x * CHUNK;
    const int nch = min(CHUNK, N_EDGES - e0);

    for (int i = tid; i < NB_P; i += BIN_T) cnt[i] = 0;
    __syncthreads();

    int es[EPT], eb[EPT], edl[EPT]; float ww[EPT];
    #pragma unroll
    for (int k = 0; k < EPT; ++k) {
        int idx = k * BIN_T + tid;
        if (idx < nch) {
            int e = e0 + idx;
            int d = dst[e];
            es[k]  = src[e];
            ww[k]  = ew[e];
            eb[k]  = d >> BK_LG;
            edl[k] = d & (BK_NODES - 1);
            atomicAdd(&cnt[eb[k]], 1);
        } else {
            eb[k] = -1;
        }
    }
    __syncthreads();

    // inclusive scan of cnt -> scn (one element per thread; NB_P == BIN_T)
    scn[tid] = cnt[tid];
    __syncthreads();
    for (int off = 1; off < NB_P; off <<= 1) {
        int v = 0;
        if (tid >= off) v = scn[tid - off];
        __syncthreads();
        if (tid >= off) scn[tid] += v;
        __syncthreads();
    }

    // reserve global ranges (one atomic per nonzero bucket)
    if (tid < NB) {
        int c = cnt[tid];
        if (c > 0) {
            int old = atomicAdd(&gcursor[tid * CUR_STRIDE], c);
            int a = BCAP - old;
            a = (a < 0) ? 0 : ((a > c) ? c : a);
            alw[tid] = a;
            gb[tid]  = tid * BCAP + old;
        } else {
            alw[tid] = 0;
            gb[tid]  = tid * BCAP;
        }
        run[tid] = 0;
    }
    __syncthreads();

    // place into staged, grouped by bucket
    #pragma unroll
    for (int k = 0; k < EPT; ++k) {
        if (eb[k] >= 0) {
            int b = eb[k];
            int p = (scn[b] - cnt[b]) + atomicAdd(&run[b], 1);
            stage[p] = make_int2(__float_as_int(ww[k]), es[k] | (edl[k] << 17));
            sbid[p]  = (unsigned short)b;
        }
    }
    __syncthreads();

    // flush: consecutive s -> contiguous runs per bucket (coalesced-ish)
    for (int s = tid; s < nch; s += BIN_T) {
        int b   = sbid[s];
        int off = s - (scn[b] - cnt[b]);
        if (off < alw[b]) ebin[(size_t)gb[b] + off] = stage[s];
    }
}

// ---------------------------------------------------------------------------
// K3: per-bucket accumulate layer 0 in LDS + fused relu/b0/W1-dot -> z1.
// 16 lanes per edge (lane = feature): z0 row read is one 64B line.
// ---------------------------------------------------------------------------
__global__ __launch_bounds__(512) void k_acc0(const int* __restrict__ gcursor,
                                              const int2* __restrict__ ebin,
                                              const float* __restrict__ z0,
                                              const float* __restrict__ b0,
                                              const float* __restrict__ W1,
                                              float* __restrict__ z1) {
    __shared__ float acc[BK_NODES * 17];
    __shared__ float b0s[16], w1s[16];
    const int tid = threadIdx.x;
    const int b   = blockIdx.x;
    if (tid < 16) { b0s[tid] = b0[tid]; w1s[tid] = W1[tid]; }
    for (int i = tid; i < BK_NODES * 17; i += 512) acc[i] = 0.f;
    __syncthreads();
    const int   ecnt = min(gcursor[b * CUR_STRIDE], BCAP);
    const int2* eb   = ebin + (size_t)b * BCAP;
    const int f = tid & 15, g = tid >> 4;       // 32 edge-groups per block
    #pragma unroll 2
    for (int i = g; i < ecnt; i += 32) {
        int2  p = eb[i];
        float w = __int_as_float(p.x);
        int   s = p.y & 0x1FFFF;
        int   dl = p.y >> 17;
        atomicAdd(&acc[dl * 17 + f], z0[(size_t)s * F_HID + f] * w);
    }
    __syncthreads();
    if (tid < BK_NODES) {
        int v = b * BK_NODES + tid;
        if (v < N_NODES) {
            float s = 0.f;
            #pragma unroll
            for (int k = 0; k < 16; ++k)
                s = fmaf(fmaxf(acc[tid * 17 + k] + b0s[k], 0.f), w1s[k], s);
            z1[v] = s;
        }
    }
}

// ---------------------------------------------------------------------------
// K4: per-bucket accumulate layer 1 in LDS + sigmoid -> out.
// ---------------------------------------------------------------------------
__global__ __launch_bounds__(512) void k_acc1(const int* __restrict__ gcursor,
                                              const int2* __restrict__ ebin,
                                              const float* __restrict__ z1,
                                              const float* __restrict__ b1,
                                              float* __restrict__ out) {
    __shared__ float acc[BK_NODES];
    const int tid = threadIdx.x;
    const int b   = blockIdx.x;
    if (tid < BK_NODES) acc[tid] = 0.f;
    __syncthreads();
    const int   ecnt = min(gcursor[b * CUR_STRIDE], BCAP);
    const int2* eb   = ebin + (size_t)b * BCAP;
    #pragma unroll 4
    for (int i = tid; i < ecnt; i += 512) {
        int2 p = eb[i];
        atomicAdd(&acc[p.y >> 17], z1[p.y & 0x1FFFF] * __int_as_float(p.x));
    }
    __syncthreads();
    if (tid < BK_NODES) {
        int v = b * BK_NODES + tid;
        if (v < N_NODES) out[v] = 1.f / (1.f + expf(-(acc[tid] + b1[0])));
    }
}

extern "C" void kernel_launch(void* const* d_in, const int* in_sizes, int n_in,
                              void* d_out, int out_size, void* d_ws, size_t ws_size,
                              hipStream_t stream) {
    const float* x   = (const float*)d_in[0];
    const int*   src = (const int*)d_in[1];
    const int*   dst = (const int*)d_in[2];
    const float* ew  = (const float*)d_in[3];
    const float* W0  = (const float*)d_in[4];
    const float* b0  = (const float*)d_in[5];
    const float* W1  = (const float*)d_in[6];
    const float* b1  = (const float*)d_in[7];
    float* out = (float*)d_out;

    // Workspace: z0 | z1 | gcursor (striped) | ebin   (~36 MB total)
    float* z0      = (float*)d_ws;                              // 6.4 MB
    float* z1      = z0 + (size_t)N_NODES * F_HID;              // 400 KB
    int*   gcursor = (int*)(z1 + N_NODES);                      // 391*64 B
    int2*  ebin    = (int2*)(gcursor + NB * CUR_STRIDE);        // 28.8 MB

    hipMemsetAsync(gcursor, 0, (size_t)NB * CUR_STRIDE * sizeof(int), stream);

    k_bin <<<(N_EDGES + CHUNK - 1) / CHUNK, BIN_T, 0, stream>>>(src, dst, ew,
                                                                gcursor, ebin);
    k_xw0 <<<(N_NODES + 63) / 64, 256, 0, stream>>>(x, W0, z0, N_NODES);
    k_acc0<<<NB, 512, 0, stream>>>(gcursor, ebin, z0, b0, W1, z1);
    k_acc1<<<NB, 512, 0, stream>>>(gcursor, ebin, z1, b1, out);
}

// Round 5
// 211.764 us; speedup vs baseline: 2.0908x; 2.0908x over previous
//
#include <hip/hip_runtime.h>

#define N_NODES 100000
#define N_EDGES 3200000
#define F_IN 128
#define F_HID 16

#define BK_LG 8
#define BK_NODES 256                                  // nodes per bucket
#define NB ((N_NODES + BK_NODES - 1) / BK_NODES)      // 391 buckets
#define NB_P 512                                      // padded scan width (== BIN_T)
#define BCAP 9216                                     // edges/bucket cap (avg 8186, +11 sigma)
#define CHUNK 4096                                    // edges per bin block
#define BIN_T 512
#define EPT (CHUNK / BIN_T)                           // 8 edges/thread
#define CUR_STRIDE 16                                 // gcursor striped: 1 counter / 64B line

// ---------------------------------------------------------------------------
// K1: z0 = x @ W0
// ---------------------------------------------------------------------------
__global__ __launch_bounds__(256) void k_xw0(const float* __restrict__ x,
                                             const float* __restrict__ W0,
                                             float* __restrict__ z0, int n) {
    __shared__ float xs[64][F_IN + 1];
    __shared__ float w0s[F_IN * F_HID];
    const int tid = threadIdx.x;
    for (int i = tid; i < F_IN * F_HID; i += 256) w0s[i] = W0[i];
    const int row0 = blockIdx.x * 64;
    for (int i = tid; i < 64 * (F_IN / 4); i += 256) {
        int r  = i / (F_IN / 4);
        int c4 = i % (F_IN / 4);
        float4 v = make_float4(0.f, 0.f, 0.f, 0.f);
        int row = row0 + r;
        if (row < n) v = ((const float4*)(x + (size_t)row * F_IN))[c4];
        xs[r][c4 * 4 + 0] = v.x; xs[r][c4 * 4 + 1] = v.y;
        xs[r][c4 * 4 + 2] = v.z; xs[r][c4 * 4 + 3] = v.w;
    }
    __syncthreads();
    const int r  = tid & 63;
    const int cg = tid >> 6;
    float a0 = 0.f, a1 = 0.f, a2 = 0.f, a3 = 0.f;
    #pragma unroll 8
    for (int k = 0; k < F_IN; ++k) {
        float xv = xs[r][k];
        a0 = fmaf(xv, w0s[k * F_HID + cg * 4 + 0], a0);
        a1 = fmaf(xv, w0s[k * F_HID + cg * 4 + 1], a1);
        a2 = fmaf(xv, w0s[k * F_HID + cg * 4 + 2], a2);
        a3 = fmaf(xv, w0s[k * F_HID + cg * 4 + 3], a3);
    }
    int row = row0 + r;
    if (row < n) {
        ((float4*)(z0 + (size_t)row * F_HID))[cg] = make_float4(a0, a1, a2, a3);
    }
}

// ---------------------------------------------------------------------------
// K2: bin edges by dst-bucket (LDS grouped, ~NB global atomics per block).
// Packed edge: .x = w bits, .y = src | (dst_local << 17).
// ---------------------------------------------------------------------------
__global__ __launch_bounds__(BIN_T) void k_bin(const int* __restrict__ src,
                                               const int* __restrict__ dst,
                                               const float* __restrict__ ew,
                                               int* __restrict__ gcursor,
                                               int2* __restrict__ ebin) {
    __shared__ int cnt[NB_P], scn[NB_P], run[NB_P], gb[NB_P], alw[NB_P];
    __shared__ int2 stage[CHUNK];
    __shared__ unsigned short sbid[CHUNK];
    const int tid = threadIdx.x;
    const int e0  = blockIdx.x * CHUNK;
    const int nch = min(CHUNK, N_EDGES - e0);

    for (int i = tid; i < NB_P; i += BIN_T) cnt[i] = 0;
    __syncthreads();

    int es[EPT], eb[EPT], edl[EPT]; float ww[EPT];
    #pragma unroll
    for (int k = 0; k < EPT; ++k) {
        int idx = k * BIN_T + tid;
        if (idx < nch) {
            int e = e0 + idx;
            int d = dst[e];
            es[k]  = src[e];
            ww[k]  = ew[e];
            eb[k]  = d >> BK_LG;
            edl[k] = d & (BK_NODES - 1);
            atomicAdd(&cnt[eb[k]], 1);
        } else {
            eb[k] = -1;
        }
    }
    __syncthreads();

    // inclusive scan of cnt -> scn
    scn[tid] = cnt[tid];
    __syncthreads();
    for (int off = 1; off < NB_P; off <<= 1) {
        int v = 0;
        if (tid >= off) v = scn[tid - off];
        __syncthreads();
        if (tid >= off) scn[tid] += v;
        __syncthreads();
    }

    // reserve global ranges (one atomic per nonzero bucket)
    if (tid < NB) {
        int c = cnt[tid];
        if (c > 0) {
            int old = atomicAdd(&gcursor[tid * CUR_STRIDE], c);
            int a = BCAP - old;
            a = (a < 0) ? 0 : ((a > c) ? c : a);
            alw[tid] = a;
            gb[tid]  = tid * BCAP + old;
        } else {
            alw[tid] = 0;
            gb[tid]  = tid * BCAP;
        }
        run[tid] = 0;
    }
    __syncthreads();

    #pragma unroll
    for (int k = 0; k < EPT; ++k) {
        if (eb[k] >= 0) {
            int b = eb[k];
            int p = (scn[b] - cnt[b]) + atomicAdd(&run[b], 1);
            stage[p] = make_int2(__float_as_int(ww[k]), es[k] | (edl[k] << 17));
            sbid[p]  = (unsigned short)b;
        }
    }
    __syncthreads();

    for (int s = tid; s < nch; s += BIN_T) {
        int b   = sbid[s];
        int off = s - (scn[b] - cnt[b]);
        if (off < alw[b]) ebin[(size_t)gb[b] + off] = stage[s];
    }
}

// ---------------------------------------------------------------------------
// K3: within-bucket counting sort by dst_local -> exact CSR (ebin2) + rowinfo.
// 3.2M LDS atomics total over 256 counters/block; zero per-edge global atomics.
// ---------------------------------------------------------------------------
__global__ __launch_bounds__(512) void k_sort(const int* __restrict__ gcursor,
                                              const int2* __restrict__ ebin,
                                              int2* __restrict__ ebin2,
                                              int2* __restrict__ rowinfo) {
    __shared__ int hist[BK_NODES], excl[BK_NODES], run[BK_NODES], tmp[BK_NODES];
    const int tid = threadIdx.x;
    const int b   = blockIdx.x;
    if (tid < BK_NODES) hist[tid] = 0;
    __syncthreads();
    const int   ecnt = min(gcursor[b * CUR_STRIDE], BCAP);
    const int2* eb   = ebin + (size_t)b * BCAP;
    for (int i = tid; i < ecnt; i += 512) {
        atomicAdd(&hist[eb[i].y >> 17], 1);
    }
    __syncthreads();
    if (tid < BK_NODES) tmp[tid] = hist[tid];
    __syncthreads();
    for (int off = 1; off < BK_NODES; off <<= 1) {
        int v = 0;
        if (tid < BK_NODES && tid >= off) v = tmp[tid - off];
        __syncthreads();
        if (tid < BK_NODES && tid >= off) tmp[tid] += v;
        __syncthreads();
    }
    if (tid < BK_NODES) {
        excl[tid] = tmp[tid] - hist[tid];
        run[tid]  = 0;
        int v = b * BK_NODES + tid;
        if (v < N_NODES)
            rowinfo[v] = make_int2(b * BCAP + excl[tid], hist[tid]);
    }
    __syncthreads();
    int2* ob = ebin2 + (size_t)b * BCAP;
    for (int i = tid; i < ecnt; i += 512) {
        int2 e = eb[i];               // L2-hit re-read (64KB slab)
        int dl = e.y >> 17;
        int p  = excl[dl] + atomicAdd(&run[dl], 1);
        ob[p] = e;
    }
}

// ---------------------------------------------------------------------------
// K4: gather SpMM layer 0 + fused relu/b0/W1-dot. One wave per node:
// 16 features x 4-way edge parallel; contiguous CSR segment; no atomics.
// ---------------------------------------------------------------------------
__global__ __launch_bounds__(256) void k_gather0(const int2* __restrict__ rowinfo,
                                                 const int2* __restrict__ ebin2,
                                                 const float* __restrict__ z0,
                                                 const float* __restrict__ b0,
                                                 const float* __restrict__ W1,
                                                 float* __restrict__ z1) {
    const int tid  = threadIdx.x;
    const int lane = tid & 63;
    const int f    = lane & 15;
    const int g    = lane >> 4;
    const int v    = blockIdx.x * 4 + (tid >> 6);
    if (v >= N_NODES) return;
    const int2 ri = rowinfo[v];
    const int2* sl = ebin2 + ri.x;
    float acc = 0.f;
    for (int j = g; j < ri.y; j += 4) {
        int2 sw = sl[j];
        acc = fmaf(z0[(size_t)(sw.y & 0x1FFFF) * F_HID + f],
                   __int_as_float(sw.x), acc);
    }
    acc += __shfl_xor(acc, 16);
    acc += __shfl_xor(acc, 32);
    float h = fmaxf(acc + b0[f], 0.f);
    float c = h * W1[f];
    #pragma unroll
    for (int off = 1; off < 16; off <<= 1) c += __shfl_xor(c, off);
    if (lane == 0) z1[v] = c;
}

// ---------------------------------------------------------------------------
// K5: gather SpMM layer 1 + sigmoid. 8 lanes per node (coalesced CSR reads).
// ---------------------------------------------------------------------------
__global__ __launch_bounds__(256) void k_gather1(const int2* __restrict__ rowinfo,
                                                 const int2* __restrict__ ebin2,
                                                 const float* __restrict__ z1,
                                                 const float* __restrict__ b1,
                                                 float* __restrict__ out) {
    const int tid = threadIdx.x;
    const int l8  = tid & 7;
    const int v   = blockIdx.x * 32 + (tid >> 3);
    if (v >= N_NODES) return;
    const int2 ri = rowinfo[v];
    const int2* sl = ebin2 + ri.x;
    float acc = 0.f;
    for (int j = l8; j < ri.y; j += 8) {
        int2 sw = sl[j];
        acc += z1[sw.y & 0x1FFFF] * __int_as_float(sw.x);
    }
    #pragma unroll
    for (int off = 1; off < 8; off <<= 1) acc += __shfl_xor(acc, off);
    if (l8 == 0) {
        float t = acc + b1[0];
        out[v] = 1.f / (1.f + expf(-t));
    }
}

extern "C" void kernel_launch(void* const* d_in, const int* in_sizes, int n_in,
                              void* d_out, int out_size, void* d_ws, size_t ws_size,
                              hipStream_t stream) {
    const float* x   = (const float*)d_in[0];
    const int*   src = (const int*)d_in[1];
    const int*   dst = (const int*)d_in[2];
    const float* ew  = (const float*)d_in[3];
    const float* W0  = (const float*)d_in[4];
    const float* b0  = (const float*)d_in[5];
    const float* W1  = (const float*)d_in[6];
    const float* b1  = (const float*)d_in[7];
    float* out = (float*)d_out;

    // Workspace (~65 MB): z0 | z1 | gcursor | rowinfo | ebin | ebin2
    float* z0      = (float*)d_ws;                              // 6.4 MB
    float* z1      = z0 + (size_t)N_NODES * F_HID;              // 400 KB
    int*   gcursor = (int*)(z1 + N_NODES);                      // 25 KB
    int2*  rowinfo = (int2*)(gcursor + NB * CUR_STRIDE);        // 800 KB
    int2*  ebin    = rowinfo + (size_t)NB * BK_NODES;           // 28.8 MB
    int2*  ebin2   = ebin + (size_t)NB * BCAP;                  // 28.8 MB

    hipMemsetAsync(gcursor, 0, (size_t)NB * CUR_STRIDE * sizeof(int), stream);

    k_bin    <<<(N_EDGES + CHUNK - 1) / CHUNK, BIN_T, 0, stream>>>(src, dst, ew,
                                                                   gcursor, ebin);
    k_xw0    <<<(N_NODES + 63) / 64, 256, 0, stream>>>(x, W0, z0, N_NODES);
    k_sort   <<<NB, 512, 0, stream>>>(gcursor, ebin, ebin2, rowinfo);
    k_gather0<<<(N_NODES + 3) / 4,   256, 0, stream>>>(rowinfo, ebin2, z0, b0, W1, z1);
    k_gather1<<<(N_NODES + 31) / 32, 256, 0, stream>>>(rowinfo, ebin2, z1, b1, out);
}

// Round 6
// 153.221 us; speedup vs baseline: 2.8897x; 1.3821x over previous
//
#include <hip/hip_runtime.h>

#define N_NODES 100000
#define N_EDGES 3200000
#define F_IN 128
#define F_HID 16

#define BK_LG 8
#define BK_NODES 256                                  // nodes per bucket
#define NB ((N_NODES + BK_NODES - 1) / BK_NODES)      // 391 buckets
#define NB_P 512                                      // padded scan width (== BIN_T)
#define BCAP 9216                                     // edges/bucket cap (avg 8186, +11 sigma)
#define CHUNK 4096                                    // edges per bin block
#define BIN_T 512
#define EPT (CHUNK / BIN_T)                           // 8 edges/thread
#define CUR_STRIDE 16                                 // gcursor striped: 1 counter / 64B line

__device__ __forceinline__ unsigned short f2bf_rne(float f) {
    unsigned u = __float_as_uint(f);
    u += 0x7FFFu + ((u >> 16) & 1u);     // round-to-nearest-even
    return (unsigned short)(u >> 16);
}

// ---------------------------------------------------------------------------
// K1: z0 = x @ W0, stored as bf16 (row = 16 x 2B = 32B -> z0 is 3.2MB, fits
// the 4MB per-XCD L2 for the gather phase).
// ---------------------------------------------------------------------------
__global__ __launch_bounds__(256) void k_xw0(const float* __restrict__ x,
                                             const float* __restrict__ W0,
                                             unsigned short* __restrict__ z0b, int n) {
    __shared__ float xs[64][F_IN + 1];
    __shared__ float w0s[F_IN * F_HID];
    const int tid = threadIdx.x;
    for (int i = tid; i < F_IN * F_HID; i += 256) w0s[i] = W0[i];
    const int row0 = blockIdx.x * 64;
    for (int i = tid; i < 64 * (F_IN / 4); i += 256) {
        int r  = i / (F_IN / 4);
        int c4 = i % (F_IN / 4);
        float4 v = make_float4(0.f, 0.f, 0.f, 0.f);
        int row = row0 + r;
        if (row < n) v = ((const float4*)(x + (size_t)row * F_IN))[c4];
        xs[r][c4 * 4 + 0] = v.x; xs[r][c4 * 4 + 1] = v.y;
        xs[r][c4 * 4 + 2] = v.z; xs[r][c4 * 4 + 3] = v.w;
    }
    __syncthreads();
    const int r  = tid & 63;
    const int cg = tid >> 6;
    float a0 = 0.f, a1 = 0.f, a2 = 0.f, a3 = 0.f;
    #pragma unroll 8
    for (int k = 0; k < F_IN; ++k) {
        float xv = xs[r][k];
        a0 = fmaf(xv, w0s[k * F_HID + cg * 4 + 0], a0);
        a1 = fmaf(xv, w0s[k * F_HID + cg * 4 + 1], a1);
        a2 = fmaf(xv, w0s[k * F_HID + cg * 4 + 2], a2);
        a3 = fmaf(xv, w0s[k * F_HID + cg * 4 + 3], a3);
    }
    int row = row0 + r;
    if (row < n) {
        ushort4 p = make_ushort4(f2bf_rne(a0), f2bf_rne(a1), f2bf_rne(a2), f2bf_rne(a3));
        *(ushort4*)(z0b + (size_t)row * F_HID + cg * 4) = p;
    }
}

// ---------------------------------------------------------------------------
// K2: bin edges by dst-bucket (LDS grouped, ~NB global atomics per block).
// Packed edge: .x = w bits, .y = src | (dst_local << 17).
// ---------------------------------------------------------------------------
__global__ __launch_bounds__(BIN_T) void k_bin(const int* __restrict__ src,
                                               const int* __restrict__ dst,
                                               const float* __restrict__ ew,
                                               int* __restrict__ gcursor,
                                               int2* __restrict__ ebin) {
    __shared__ int cnt[NB_P], scn[NB_P], run[NB_P], gb[NB_P], alw[NB_P];
    __shared__ int2 stage[CHUNK];
    __shared__ unsigned short sbid[CHUNK];
    const int tid = threadIdx.x;
    const int e0  = blockIdx.x * CHUNK;
    const int nch = min(CHUNK, N_EDGES - e0);

    for (int i = tid; i < NB_P; i += BIN_T) cnt[i] = 0;
    __syncthreads();

    int es[EPT], eb[EPT], edl[EPT]; float ww[EPT];
    #pragma unroll
    for (int k = 0; k < EPT; ++k) {
        int idx = k * BIN_T + tid;
        if (idx < nch) {
            int e = e0 + idx;
            int d = dst[e];
            es[k]  = src[e];
            ww[k]  = ew[e];
            eb[k]  = d >> BK_LG;
            edl[k] = d & (BK_NODES - 1);
            atomicAdd(&cnt[eb[k]], 1);
        } else {
            eb[k] = -1;
        }
    }
    __syncthreads();

    scn[tid] = cnt[tid];
    __syncthreads();
    for (int off = 1; off < NB_P; off <<= 1) {
        int v = 0;
        if (tid >= off) v = scn[tid - off];
        __syncthreads();
        if (tid >= off) scn[tid] += v;
        __syncthreads();
    }

    if (tid < NB) {
        int c = cnt[tid];
        if (c > 0) {
            int old = atomicAdd(&gcursor[tid * CUR_STRIDE], c);
            int a = BCAP - old;
            a = (a < 0) ? 0 : ((a > c) ? c : a);
            alw[tid] = a;
            gb[tid]  = tid * BCAP + old;
        } else {
            alw[tid] = 0;
            gb[tid]  = tid * BCAP;
        }
        run[tid] = 0;
    }
    __syncthreads();

    #pragma unroll
    for (int k = 0; k < EPT; ++k) {
        if (eb[k] >= 0) {
            int b = eb[k];
            int p = (scn[b] - cnt[b]) + atomicAdd(&run[b], 1);
            stage[p] = make_int2(__float_as_int(ww[k]), es[k] | (edl[k] << 17));
            sbid[p]  = (unsigned short)b;
        }
    }
    __syncthreads();

    for (int s = tid; s < nch; s += BIN_T) {
        int b   = sbid[s];
        int off = s - (scn[b] - cnt[b]);
        if (off < alw[b]) ebin[(size_t)gb[b] + off] = stage[s];
    }
}

// ---------------------------------------------------------------------------
// K3: within-bucket counting sort by dst_local -> exact CSR (ebin2) + rowinfo.
// ---------------------------------------------------------------------------
__global__ __launch_bounds__(512) void k_sort(const int* __restrict__ gcursor,
                                              const int2* __restrict__ ebin,
                                              int2* __restrict__ ebin2,
                                              int2* __restrict__ rowinfo) {
    __shared__ int hist[BK_NODES], excl[BK_NODES], run[BK_NODES], tmp[BK_NODES];
    const int tid = threadIdx.x;
    const int b   = blockIdx.x;
    if (tid < BK_NODES) hist[tid] = 0;
    __syncthreads();
    const int   ecnt = min(gcursor[b * CUR_STRIDE], BCAP);
    const int2* eb   = ebin + (size_t)b * BCAP;
    for (int i = tid; i < ecnt; i += 512) {
        atomicAdd(&hist[eb[i].y >> 17], 1);
    }
    __syncthreads();
    if (tid < BK_NODES) tmp[tid] = hist[tid];
    __syncthreads();
    for (int off = 1; off < BK_NODES; off <<= 1) {
        int v = 0;
        if (tid < BK_NODES && tid >= off) v = tmp[tid - off];
        __syncthreads();
        if (tid < BK_NODES && tid >= off) tmp[tid] += v;
        __syncthreads();
    }
    if (tid < BK_NODES) {
        excl[tid] = tmp[tid] - hist[tid];
        run[tid]  = 0;
        int v = b * BK_NODES + tid;
        if (v < N_NODES)
            rowinfo[v] = make_int2(b * BCAP + excl[tid], hist[tid]);
    }
    __syncthreads();
    int2* ob = ebin2 + (size_t)b * BCAP;
    for (int i = tid; i < ecnt; i += 512) {
        int2 e = eb[i];
        int dl = e.y >> 17;
        int p  = excl[dl] + atomicAdd(&run[dl], 1);
        ob[p] = e;
    }
}

// ---------------------------------------------------------------------------
// K4: gather SpMM layer 0 + fused relu/b0/W1-dot. One wave per node:
// 8 feature-pair lanes (bf16x2) x 8-way edge parallel, unroll 2 (zero-pad).
// ---------------------------------------------------------------------------
__global__ __launch_bounds__(256) void k_gather0(const int2* __restrict__ rowinfo,
                                                 const int2* __restrict__ ebin2,
                                                 const unsigned short* __restrict__ z0b,
                                                 const float* __restrict__ b0,
                                                 const float* __restrict__ W1,
                                                 float* __restrict__ z1) {
    const int tid  = threadIdx.x;
    const int lane = tid & 63;
    const int f2   = lane & 7;          // feature pair: features 2*f2, 2*f2+1
    const int g    = lane >> 3;         // 0..7 edge-parallel group
    const int v    = blockIdx.x * 4 + (tid >> 6);
    if (v >= N_NODES) return;
    const int2 ri = rowinfo[v];
    const int2* sl = ebin2 + ri.x;
    const int dv = ri.y;
    float acc0 = 0.f, acc1 = 0.f;
    const int2 zed = make_int2(0, 0);   // w = 0.0f -> no-op edge
    for (int j = g; j < dv; j += 16) {
        int2 e0 = sl[j];
        int2 e1 = (j + 8 < dv) ? sl[j + 8] : zed;
        unsigned u0 = *(const unsigned*)(z0b + (size_t)(e0.y & 0x1FFFF) * F_HID + f2 * 2);
        unsigned u1 = *(const unsigned*)(z0b + (size_t)(e1.y & 0x1FFFF) * F_HID + f2 * 2);
        float w0 = __int_as_float(e0.x), w1 = __int_as_float(e1.x);
        acc0 = fmaf(__uint_as_float(u0 << 16),          w0, acc0);
        acc1 = fmaf(__uint_as_float(u0 & 0xFFFF0000u),  w0, acc1);
        acc0 = fmaf(__uint_as_float(u1 << 16),          w1, acc0);
        acc1 = fmaf(__uint_as_float(u1 & 0xFFFF0000u),  w1, acc1);
    }
    // reduce across the 8 g-groups (lane bits 3,4,5)
    acc0 += __shfl_xor(acc0, 8);  acc1 += __shfl_xor(acc1, 8);
    acc0 += __shfl_xor(acc0, 16); acc1 += __shfl_xor(acc1, 16);
    acc0 += __shfl_xor(acc0, 32); acc1 += __shfl_xor(acc1, 32);
    float2 bb = *(const float2*)(b0 + f2 * 2);
    float2 wv = *(const float2*)(W1 + f2 * 2);
    float c = fmaxf(acc0 + bb.x, 0.f) * wv.x + fmaxf(acc1 + bb.y, 0.f) * wv.y;
    // reduce across the 8 feature pairs (lane bits 0,1,2)
    c += __shfl_xor(c, 1);
    c += __shfl_xor(c, 2);
    c += __shfl_xor(c, 4);
    if (lane == 0) z1[v] = c;
}

// ---------------------------------------------------------------------------
// K5: gather SpMM layer 1 + sigmoid. 8 lanes per node, unroll 2 (zero-pad).
// ---------------------------------------------------------------------------
__global__ __launch_bounds__(256) void k_gather1(const int2* __restrict__ rowinfo,
                                                 const int2* __restrict__ ebin2,
                                                 const float* __restrict__ z1,
                                                 const float* __restrict__ b1,
                                                 float* __restrict__ out) {
    const int tid = threadIdx.x;
    const int l8  = tid & 7;
    const int v   = blockIdx.x * 32 + (tid >> 3);
    if (v >= N_NODES) return;
    const int2 ri = rowinfo[v];
    const int2* sl = ebin2 + ri.x;
    const int dv = ri.y;
    float acc = 0.f;
    const int2 zed = make_int2(0, 0);
    for (int j = l8; j < dv; j += 16) {
        int2 e0 = sl[j];
        int2 e1 = (j + 8 < dv) ? sl[j + 8] : zed;
        acc = fmaf(z1[e0.y & 0x1FFFF], __int_as_float(e0.x), acc);
        acc = fmaf(z1[e1.y & 0x1FFFF], __int_as_float(e1.x), acc);
    }
    #pragma unroll
    for (int off = 1; off < 8; off <<= 1) acc += __shfl_xor(acc, off);
    if (l8 == 0) {
        float t = acc + b1[0];
        out[v] = 1.f / (1.f + expf(-t));
    }
}

extern "C" void kernel_launch(void* const* d_in, const int* in_sizes, int n_in,
                              void* d_out, int out_size, void* d_ws, size_t ws_size,
                              hipStream_t stream) {
    const float* x   = (const float*)d_in[0];
    const int*   src = (const int*)d_in[1];
    const int*   dst = (const int*)d_in[2];
    const float* ew  = (const float*)d_in[3];
    const float* W0  = (const float*)d_in[4];
    const float* b0  = (const float*)d_in[5];
    const float* W1  = (const float*)d_in[6];
    const float* b1  = (const float*)d_in[7];
    float* out = (float*)d_out;

    // Workspace (~62 MB): z0b | z1 | gcursor | rowinfo | ebin | ebin2
    unsigned short* z0b = (unsigned short*)d_ws;                // 3.2 MB
    float* z1      = (float*)(z0b + (size_t)N_NODES * F_HID);   // 400 KB
    int*   gcursor = (int*)(z1 + N_NODES);                      // 25 KB
    int2*  rowinfo = (int2*)(gcursor + NB * CUR_STRIDE);        // 800 KB
    int2*  ebin    = rowinfo + (size_t)NB * BK_NODES;           // 28.8 MB
    int2*  ebin2   = ebin + (size_t)NB * BCAP;                  // 28.8 MB

    hipMemsetAsync(gcursor, 0, (size_t)NB * CUR_STRIDE * sizeof(int), stream);

    k_bin    <<<(N_EDGES + CHUNK - 1) / CHUNK, BIN_T, 0, stream>>>(src, dst, ew,
                                                                   gcursor, ebin);
    k_xw0    <<<(N_NODES + 63) / 64, 256, 0, stream>>>(x, W0, z0b, N_NODES);
    k_sort   <<<NB, 512, 0, stream>>>(gcursor, ebin, ebin2, rowinfo);
    k_gather0<<<(N_NODES + 3) / 4,   256, 0, stream>>>(rowinfo, ebin2, z0b, b0, W1, z1);
    k_gather1<<<(N_NODES + 31) / 32, 256, 0, stream>>>(rowinfo, ebin2, z1, b1, out);
}

// Round 7
// 149.093 us; speedup vs baseline: 2.9697x; 1.0277x over previous
//
#include <hip/hip_runtime.h>

#define N_NODES 100000
#define N_EDGES 3200000
#define F_IN 128
#define F_HID 16

#define BK_LG 7
#define BK_NODES 128                                  // nodes per bucket
#define NB ((N_NODES + BK_NODES - 1) / BK_NODES)      // 782 buckets
#define NB_P 1024                                     // padded scan width
#define BCAP 4800                                     // edges/bucket cap (avg 4093, +11 sigma)
#define CHUNK 4096                                    // edges per bin block
#define BIN_T 512
#define EPT (CHUNK / BIN_T)                           // 8 edges/thread
#define CUR_STRIDE 16                                 // gcursor striped: 1 counter / 64B line

__device__ __forceinline__ unsigned short f2bf_rne(float f) {
    unsigned u = __float_as_uint(f);
    u += 0x7FFFu + ((u >> 16) & 1u);     // round-to-nearest-even
    return (unsigned short)(u >> 16);
}

// ---------------------------------------------------------------------------
// K1: z0 = x @ W0, stored bf16 (row = 32B; z0b = 3.2MB, fits per-XCD L2).
// ---------------------------------------------------------------------------
__global__ __launch_bounds__(256) void k_xw0(const float* __restrict__ x,
                                             const float* __restrict__ W0,
                                             unsigned short* __restrict__ z0b, int n) {
    __shared__ float xs[64][F_IN + 1];
    __shared__ float w0s[F_IN * F_HID];
    const int tid = threadIdx.x;
    for (int i = tid; i < F_IN * F_HID; i += 256) w0s[i] = W0[i];
    const int row0 = blockIdx.x * 64;
    for (int i = tid; i < 64 * (F_IN / 4); i += 256) {
        int r  = i / (F_IN / 4);
        int c4 = i % (F_IN / 4);
        float4 v = make_float4(0.f, 0.f, 0.f, 0.f);
        int row = row0 + r;
        if (row < n) v = ((const float4*)(x + (size_t)row * F_IN))[c4];
        xs[r][c4 * 4 + 0] = v.x; xs[r][c4 * 4 + 1] = v.y;
        xs[r][c4 * 4 + 2] = v.z; xs[r][c4 * 4 + 3] = v.w;
    }
    __syncthreads();
    const int r  = tid & 63;
    const int cg = tid >> 6;
    float a0 = 0.f, a1 = 0.f, a2 = 0.f, a3 = 0.f;
    #pragma unroll 8
    for (int k = 0; k < F_IN; ++k) {
        float xv = xs[r][k];
        a0 = fmaf(xv, w0s[k * F_HID + cg * 4 + 0], a0);
        a1 = fmaf(xv, w0s[k * F_HID + cg * 4 + 1], a1);
        a2 = fmaf(xv, w0s[k * F_HID + cg * 4 + 2], a2);
        a3 = fmaf(xv, w0s[k * F_HID + cg * 4 + 3], a3);
    }
    int row = row0 + r;
    if (row < n) {
        ushort4 p = make_ushort4(f2bf_rne(a0), f2bf_rne(a1), f2bf_rne(a2), f2bf_rne(a3));
        *(ushort4*)(z0b + (size_t)row * F_HID + cg * 4) = p;
    }
}

// ---------------------------------------------------------------------------
// K2: bin edges by 128-node dst-bucket. LDS count -> wave-shuffle scan ->
// global range reserve (~NB atomics/block, striped lines) -> LDS-grouped
// placement -> coalesced flush. Packed edge: .x = w, .y = src | (dl << 17).
// ---------------------------------------------------------------------------
__global__ __launch_bounds__(BIN_T) void k_bin(const int* __restrict__ src,
                                               const int* __restrict__ dst,
                                               const float* __restrict__ ew,
                                               int* __restrict__ gcursor,
                                               int2* __restrict__ ebin) {
    __shared__ int cnt[NB_P], excl[NB_P], run[NB_P], gb[NB_P], alw[NB_P];
    __shared__ int2 stage[CHUNK];
    __shared__ unsigned short sbid[CHUNK];
    __shared__ int wsum[8];
    const int tid  = threadIdx.x;
    const int lane = tid & 63, wid = tid >> 6;
    const int e0   = blockIdx.x * CHUNK;
    const int nch  = min(CHUNK, N_EDGES - e0);

    for (int i = tid; i < NB_P; i += BIN_T) cnt[i] = 0;
    __syncthreads();

    int es[EPT], eb[EPT], edl[EPT]; float ww[EPT];
    #pragma unroll
    for (int k = 0; k < EPT; ++k) {
        int idx = k * BIN_T + tid;
        if (idx < nch) {
            int e = e0 + idx;
            int d = dst[e];
            es[k]  = src[e];
            ww[k]  = ew[e];
            eb[k]  = d >> BK_LG;
            edl[k] = d & (BK_NODES - 1);
            atomicAdd(&cnt[eb[k]], 1);
        } else {
            eb[k] = -1;
        }
    }
    __syncthreads();

    // exclusive scan of cnt[0..1024) via wave shuffles (2 elems/thread)
    {
        int c0 = cnt[2 * tid], c1 = cnt[2 * tid + 1];
        int s  = c0 + c1;
        int sc = s;
        #pragma unroll
        for (int off = 1; off < 64; off <<= 1) {
            int t = __shfl_up(sc, off);
            if (lane >= off) sc += t;
        }
        if (lane == 63) wsum[wid] = sc;
        __syncthreads();
        if (wid == 0 && lane < 8) {
            int wv = wsum[lane];
            #pragma unroll
            for (int off = 1; off < 8; off <<= 1) {
                int t = __shfl_up(wv, off);
                if (lane >= off) wv += t;
            }
            wsum[lane] = wv;
        }
        __syncthreads();
        int base = (wid > 0 ? wsum[wid - 1] : 0) + (sc - s);
        excl[2 * tid]     = base;
        excl[2 * tid + 1] = base + c0;
    }
    __syncthreads();

    // reserve global ranges (one atomic per nonzero bucket)
    for (int b = tid; b < NB; b += BIN_T) {
        int c = cnt[b];
        if (c > 0) {
            int old = atomicAdd(&gcursor[b * CUR_STRIDE], c);
            int a = BCAP - old;
            a = (a < 0) ? 0 : ((a > c) ? c : a);
            alw[b] = a;
            gb[b]  = b * BCAP + old;
        } else {
            alw[b] = 0;
            gb[b]  = b * BCAP;
        }
        run[b] = 0;
    }
    __syncthreads();

    #pragma unroll
    for (int k = 0; k < EPT; ++k) {
        if (eb[k] >= 0) {
            int b = eb[k];
            int p = excl[b] + atomicAdd(&run[b], 1);
            stage[p] = make_int2(__float_as_int(ww[k]), es[k] | (edl[k] << 17));
            sbid[p]  = (unsigned short)b;
        }
    }
    __syncthreads();

    for (int s = tid; s < nch; s += BIN_T) {
        int b   = sbid[s];
        int off = s - excl[b];
        if (off < alw[b]) ebin[(size_t)gb[b] + off] = stage[s];
    }
}

// ---------------------------------------------------------------------------
// K3: FUSED sort + gather layer 0 + relu/b0/W1-dot. One block per bucket:
// stage bucket edges in LDS (one coalesced global read), build per-node rank
// index in LDS, then gather z0b per node from LDS-sorted edges. ebin2 gone.
// ---------------------------------------------------------------------------
__global__ __launch_bounds__(512) void k_sg0(const int* __restrict__ gcursor,
                                             const int2* __restrict__ ebin,
                                             const unsigned short* __restrict__ z0b,
                                             const float* __restrict__ b0,
                                             const float* __restrict__ W1,
                                             float* __restrict__ z1) {
    __shared__ int2 stage[BCAP];                 // 38.4 KB
    __shared__ unsigned short idx[BCAP];         // 9.6 KB
    __shared__ int hist[BK_NODES], scn[BK_NODES], run[BK_NODES];
    __shared__ float b0s[16], w1s[16];
    const int tid  = threadIdx.x;
    const int lane = tid & 63, wid = tid >> 6;
    const int b    = blockIdx.x;
    if (tid < 16)        { b0s[tid] = b0[tid]; w1s[tid] = W1[tid]; }
    if (tid < BK_NODES)  hist[tid] = 0;
    __syncthreads();

    const int   ecnt = min(gcursor[b * CUR_STRIDE], BCAP);
    const int2* eb   = ebin + (size_t)b * BCAP;
    for (int i = tid; i < ecnt; i += 512) {
        int2 e = eb[i];
        stage[i] = e;
        atomicAdd(&hist[e.y >> 17], 1);
    }
    __syncthreads();

    // exclusive scan of hist[0..128) (barrier-doubling, cheap vs phase d)
    if (tid < BK_NODES) scn[tid] = hist[tid];
    __syncthreads();
    for (int off = 1; off < BK_NODES; off <<= 1) {
        int v = 0;
        if (tid < BK_NODES && tid >= off) v = scn[tid - off];
        __syncthreads();
        if (tid < BK_NODES && tid >= off) scn[tid] += v;
        __syncthreads();
    }
    if (tid < BK_NODES) { int e = scn[tid] - hist[tid]; scn[tid] = e; run[tid] = 0; }
    __syncthreads();

    // rank scatter: idx[scn[dl]+r] = LDS position of edge
    for (int i = tid; i < ecnt; i += 512) {
        int dl = stage[i].y >> 17;
        int r  = atomicAdd(&run[dl], 1);
        idx[scn[dl] + r] = (unsigned short)i;
    }
    __syncthreads();

    // gather: wave w handles local nodes w, w+8, ... (16 nodes each)
    for (int n = wid; n < BK_NODES; n += 8) {
        const int v = b * BK_NODES + n;
        if (v >= N_NODES) continue;              // wave-uniform
        const int beg = scn[n], dv = hist[n];
        const int f2  = lane & 7;                // feature pair
        const int g   = lane >> 3;               // 0..7 edge group
        float acc0 = 0.f, acc1 = 0.f;
        for (int j = g; j < dv; j += 16) {
            int2 e0 = stage[idx[beg + j]];
            int  j1 = j + 8;
            int2 e1 = (j1 < dv) ? stage[idx[beg + j1]] : stage[0];
            if (j1 >= dv) e1.x = 0;              // w=0 no-op, addr stays valid
            unsigned u0 = *(const unsigned*)(z0b + (size_t)(e0.y & 0x1FFFF) * F_HID + f2 * 2);
            unsigned u1 = *(const unsigned*)(z0b + (size_t)(e1.y & 0x1FFFF) * F_HID + f2 * 2);
            float w0 = __int_as_float(e0.x), w1 = __int_as_float(e1.x);
            acc0 = fmaf(__uint_as_float(u0 << 16),         w0, acc0);
            acc1 = fmaf(__uint_as_float(u0 & 0xFFFF0000u), w0, acc1);
            acc0 = fmaf(__uint_as_float(u1 << 16),         w1, acc0);
            acc1 = fmaf(__uint_as_float(u1 & 0xFFFF0000u), w1, acc1);
        }
        acc0 += __shfl_xor(acc0, 8);  acc1 += __shfl_xor(acc1, 8);
        acc0 += __shfl_xor(acc0, 16); acc1 += __shfl_xor(acc1, 16);
        acc0 += __shfl_xor(acc0, 32); acc1 += __shfl_xor(acc1, 32);
        float c = fmaxf(acc0 + b0s[f2 * 2], 0.f) * w1s[f2 * 2]
                + fmaxf(acc1 + b0s[f2 * 2 + 1], 0.f) * w1s[f2 * 2 + 1];
        c += __shfl_xor(c, 1);
        c += __shfl_xor(c, 2);
        c += __shfl_xor(c, 4);
        if (lane == 0) z1[v] = c;
    }
}

// ---------------------------------------------------------------------------
// K4: layer 1 straight from bucket-grouped ebin: one LDS atomic per edge
// into a 128-float accumulator, fused sigmoid. No sorted edges needed.
// ---------------------------------------------------------------------------
__global__ __launch_bounds__(256) void k_g1(const int* __restrict__ gcursor,
                                            const int2* __restrict__ ebin,
                                            const float* __restrict__ z1,
                                            const float* __restrict__ b1,
                                            float* __restrict__ out) {
    __shared__ float acc[BK_NODES];
    const int tid = threadIdx.x;
    const int b   = blockIdx.x;
    if (tid < BK_NODES) acc[tid] = 0.f;
    __syncthreads();
    const int   ecnt = min(gcursor[b * CUR_STRIDE], BCAP);
    const int2* eb   = ebin + (size_t)b * BCAP;
    for (int i = tid; i < ecnt; i += 512) {
        int2 e0 = eb[i];
        int  i1 = i + 256;
        int2 e1 = (i1 < ecnt) ? eb[i1] : make_int2(0, 0);
        float m0 = z1[e0.y & 0x1FFFF] * __int_as_float(e0.x);
        float m1 = z1[e1.y & 0x1FFFF] * __int_as_float(e1.x);
        atomicAdd(&acc[e0.y >> 17], m0);
        if (i1 < ecnt) atomicAdd(&acc[e1.y >> 17], m1);
    }
    __syncthreads();
    if (tid < BK_NODES) {
        int v = b * BK_NODES + tid;
        if (v < N_NODES) out[v] = 1.f / (1.f + expf(-(acc[tid] + b1[0])));
    }
}

extern "C" void kernel_launch(void* const* d_in, const int* in_sizes, int n_in,
                              void* d_out, int out_size, void* d_ws, size_t ws_size,
                              hipStream_t stream) {
    const float* x   = (const float*)d_in[0];
    const int*   src = (const int*)d_in[1];
    const int*   dst = (const int*)d_in[2];
    const float* ew  = (const float*)d_in[3];
    const float* W0  = (const float*)d_in[4];
    const float* b0  = (const float*)d_in[5];
    const float* W1  = (const float*)d_in[6];
    const float* b1  = (const float*)d_in[7];
    float* out = (float*)d_out;

    // Workspace (~34 MB): z0b | z1 | gcursor | ebin
    unsigned short* z0b = (unsigned short*)d_ws;                // 3.2 MB
    float* z1      = (float*)(z0b + (size_t)N_NODES * F_HID);   // 400 KB
    int*   gcursor = (int*)(z1 + N_NODES);                      // 50 KB
    int2*  ebin    = (int2*)(gcursor + NB * CUR_STRIDE);        // 30 MB

    hipMemsetAsync(gcursor, 0, (size_t)NB * CUR_STRIDE * sizeof(int), stream);

    k_bin <<<(N_EDGES + CHUNK - 1) / CHUNK, BIN_T, 0, stream>>>(src, dst, ew,
                                                                gcursor, ebin);
    k_xw0 <<<(N_NODES + 63) / 64, 256, 0, stream>>>(x, W0, z0b, N_NODES);
    k_sg0 <<<NB, 512, 0, stream>>>(gcursor, ebin, z0b, b0, W1, z1);
    k_g1  <<<NB, 256, 0, stream>>>(gcursor, ebin, z1, b1, out);
}

// Round 8
// 148.151 us; speedup vs baseline: 2.9886x; 1.0064x over previous
//
#include <hip/hip_runtime.h>

#define N_NODES 100000
#define N_EDGES 3200000
#define F_IN 128
#define F_HID 16

// fine buckets (consumer-facing)
#define BK_LG 7
#define BK_NODES 128
#define NB ((N_NODES + BK_NODES - 1) / BK_NODES)      // 782
#define BCAPF 4800                                    // avg 4093, +11 sigma
// coarse buckets (pass-1)
#define CLG 10
#define CNODES 1024                                   // = 8 fine buckets
#define NBC ((N_NODES + CNODES - 1) / CNODES)         // 98
#define NBC_P 128
#define BCAPC 34816                                   // avg 32768, +11 sigma
#define CPB2 9                                        // pass-2 chunks per coarse
#define CHUNK 4096
#define BIN_T 512
#define EPT (CHUNK / BIN_T)                           // 8
#define CUR_STRIDE 16                                 // striped cursors

__device__ __forceinline__ unsigned short f2bf_rne(float f) {
    unsigned u = __float_as_uint(f);
    u += 0x7FFFu + ((u >> 16) & 1u);
    return (unsigned short)(u >> 16);
}

// ---------------------------------------------------------------------------
// K1: z0 = x @ W0, stored bf16 (z0b = 3.2MB, fits per-XCD L2).
// ---------------------------------------------------------------------------
__global__ __launch_bounds__(256) void k_xw0(const float* __restrict__ x,
                                             const float* __restrict__ W0,
                                             unsigned short* __restrict__ z0b, int n) {
    __shared__ float xs[64][F_IN + 1];
    __shared__ float w0s[F_IN * F_HID];
    const int tid = threadIdx.x;
    for (int i = tid; i < F_IN * F_HID; i += 256) w0s[i] = W0[i];
    const int row0 = blockIdx.x * 64;
    for (int i = tid; i < 64 * (F_IN / 4); i += 256) {
        int r  = i / (F_IN / 4);
        int c4 = i % (F_IN / 4);
        float4 v = make_float4(0.f, 0.f, 0.f, 0.f);
        int row = row0 + r;
        if (row < n) v = ((const float4*)(x + (size_t)row * F_IN))[c4];
        xs[r][c4 * 4 + 0] = v.x; xs[r][c4 * 4 + 1] = v.y;
        xs[r][c4 * 4 + 2] = v.z; xs[r][c4 * 4 + 3] = v.w;
    }
    __syncthreads();
    const int r  = tid & 63;
    const int cg = tid >> 6;
    float a0 = 0.f, a1 = 0.f, a2 = 0.f, a3 = 0.f;
    #pragma unroll 8
    for (int k = 0; k < F_IN; ++k) {
        float xv = xs[r][k];
        a0 = fmaf(xv, w0s[k * F_HID + cg * 4 + 0], a0);
        a1 = fmaf(xv, w0s[k * F_HID + cg * 4 + 1], a1);
        a2 = fmaf(xv, w0s[k * F_HID + cg * 4 + 2], a2);
        a3 = fmaf(xv, w0s[k * F_HID + cg * 4 + 3], a3);
    }
    int row = row0 + r;
    if (row < n) {
        ushort4 p = make_ushort4(f2bf_rne(a0), f2bf_rne(a1), f2bf_rne(a2), f2bf_rne(a3));
        *(ushort4*)(z0b + (size_t)row * F_HID + cg * 4) = p;
    }
}

// ---------------------------------------------------------------------------
// K2a: pass-1 bin by coarse 1024-node bucket. Runs ~42 edges (336B) ->
// near-coalesced flush. Packed: .x = w, .y = src | (dst_coarse_local << 17).
// ---------------------------------------------------------------------------
__global__ __launch_bounds__(BIN_T) void k_bin1(const int* __restrict__ src,
                                                const int* __restrict__ dst,
                                                const float* __restrict__ ew,
                                                int* __restrict__ cursorC,
                                                int2* __restrict__ ebinC) {
    __shared__ int cnt[NBC_P], excl[NBC_P], run[NBC_P], gb[NBC_P], alw[NBC_P];
    __shared__ int2 stage[CHUNK];
    __shared__ unsigned char sbid[CHUNK];
    const int tid = threadIdx.x;
    const int e0  = blockIdx.x * CHUNK;
    const int nch = min(CHUNK, N_EDGES - e0);

    for (int i = tid; i < NBC_P; i += BIN_T) cnt[i] = 0;
    __syncthreads();

    int es[EPT], eb[EPT], edl[EPT]; float ww[EPT];
    #pragma unroll
    for (int k = 0; k < EPT; ++k) {
        int idx = k * BIN_T + tid;
        if (idx < nch) {
            int e = e0 + idx;
            int d = dst[e];
            es[k]  = src[e];
            ww[k]  = ew[e];
            eb[k]  = d >> CLG;
            edl[k] = d & (CNODES - 1);
            atomicAdd(&cnt[eb[k]], 1);
        } else {
            eb[k] = -1;
        }
    }
    __syncthreads();

    // exclusive scan of cnt[0..128) via LDS doubling
    if (tid < NBC_P) excl[tid] = cnt[tid];
    __syncthreads();
    for (int off = 1; off < NBC_P; off <<= 1) {
        int v = 0;
        if (tid < NBC_P && tid >= off) v = excl[tid - off];
        __syncthreads();
        if (tid < NBC_P && tid >= off) excl[tid] += v;
        __syncthreads();
    }
    if (tid < NBC_P) excl[tid] -= cnt[tid];
    __syncthreads();

    if (tid < NBC) {
        int c = cnt[tid];
        if (c > 0) {
            int old = atomicAdd(&cursorC[tid * CUR_STRIDE], c);
            int a = BCAPC - old;
            a = (a < 0) ? 0 : ((a > c) ? c : a);
            alw[tid] = a;
            gb[tid]  = tid * BCAPC + old;
        } else {
            alw[tid] = 0;
            gb[tid]  = tid * BCAPC;
        }
        run[tid] = 0;
    }
    __syncthreads();

    #pragma unroll
    for (int k = 0; k < EPT; ++k) {
        if (eb[k] >= 0) {
            int b = eb[k];
            int p = excl[b] + atomicAdd(&run[b], 1);
            stage[p] = make_int2(__float_as_int(ww[k]), es[k] | (edl[k] << 17));
            sbid[p]  = (unsigned char)b;
        }
    }
    __syncthreads();

    for (int s = tid; s < nch; s += BIN_T) {
        int b   = sbid[s];
        int off = s - excl[b];
        if (off < alw[b]) ebinC[(size_t)gb[b] + off] = stage[s];
    }
}

// ---------------------------------------------------------------------------
// K2b: pass-2: split each coarse slab 8-ways into fine 128-node buckets.
// Reads contiguous, runs ~480 edges -> fully coalesced writes.
// Per-wave-replicated LDS counters avoid atomic serialization.
// ---------------------------------------------------------------------------
__global__ __launch_bounds__(BIN_T) void k_bin2(const int* __restrict__ cursorC,
                                                const int2* __restrict__ ebinC,
                                                int* __restrict__ cursorF,
                                                int2* __restrict__ ebinF) {
    __shared__ int cntw[64], runw[64], base[64];
    __shared__ int totals[8], excl_s[8], gb8[8], alw8[8];
    __shared__ int2 stage[CHUNK];
    __shared__ unsigned char sbid[CHUNK];
    const int tid = threadIdx.x;
    const int wid = tid >> 6;
    const int c   = blockIdx.x / CPB2;
    const int ck  = blockIdx.x % CPB2;
    const int ecnt = min(cursorC[c * CUR_STRIDE], BCAPC);
    const int beg  = ck * CHUNK;
    const int n2   = min(CHUNK, ecnt - beg);
    if (n2 <= 0) return;                         // uniform exit before barriers
    const int2* eC = ebinC + (size_t)c * BCAPC + beg;

    if (tid < 64) { cntw[tid] = 0; runw[tid] = 0; }
    __syncthreads();

    int fid[EPT]; int2 pk[EPT];
    #pragma unroll
    for (int k = 0; k < EPT; ++k) {
        int idx = k * BIN_T + tid;
        if (idx < n2) {
            int2 e = eC[idx];
            int dlc = e.y >> 17;                 // 0..1023 within coarse
            int f   = dlc >> BK_LG;              // 0..7 fine within coarse
            fid[k]  = f;
            pk[k]   = make_int2(e.x, (e.y & 0x1FFFF) | ((dlc & (BK_NODES - 1)) << 17));
            atomicAdd(&cntw[f * 8 + wid], 1);
        } else {
            fid[k] = -1;
        }
    }
    __syncthreads();

    if (tid < 8) {
        int t = 0;
        #pragma unroll
        for (int w = 0; w < 8; ++w) t += cntw[tid * 8 + w];
        totals[tid] = t;
    }
    __syncthreads();
    if (tid < 8) {
        int e = 0;
        for (int f = 0; f < 8; ++f) if (f < tid) e += totals[f];
        excl_s[tid] = e;
        int t = totals[tid];
        int fb = c * 8 + tid;                    // global fine bucket id
        if (t > 0 && fb < NB) {
            int old = atomicAdd(&cursorF[fb * CUR_STRIDE], t);
            int a = BCAPF - old;
            a = (a < 0) ? 0 : ((a > t) ? t : a);
            alw8[tid] = a;
            gb8[tid]  = fb * BCAPF + old;
        } else {
            alw8[tid] = 0;
            gb8[tid]  = 0;
        }
    }
    __syncthreads();
    if (tid < 64) {
        int f = tid >> 3, w = tid & 7;
        int bb = excl_s[f];
        for (int w2 = 0; w2 < 8; ++w2) if (w2 < w) bb += cntw[f * 8 + w2];
        base[tid] = bb;
    }
    __syncthreads();

    #pragma unroll
    for (int k = 0; k < EPT; ++k) {
        if (fid[k] >= 0) {
            int slot = fid[k] * 8 + wid;
            int p = base[slot] + atomicAdd(&runw[slot], 1);
            stage[p] = pk[k];
            sbid[p]  = (unsigned char)fid[k];
        }
    }
    __syncthreads();

    for (int s = tid; s < n2; s += BIN_T) {
        int f   = sbid[s];
        int off = s - excl_s[f];
        if (off < alw8[f]) ebinF[(size_t)gb8[f] + off] = stage[s];
    }
}

// ---------------------------------------------------------------------------
// K3: FUSED sort + gather layer 0 + relu/b0/W1-dot (one block per fine bucket).
// ---------------------------------------------------------------------------
__global__ __launch_bounds__(512) void k_sg0(const int* __restrict__ cursorF,
                                             const int2* __restrict__ ebinF,
                                             const unsigned short* __restrict__ z0b,
                                             const float* __restrict__ b0,
                                             const float* __restrict__ W1,
                                             float* __restrict__ z1) {
    __shared__ int2 stage[BCAPF];
    __shared__ unsigned short idx[BCAPF];
    __shared__ int hist[BK_NODES], scn[BK_NODES], run[BK_NODES];
    __shared__ float b0s[16], w1s[16];
    const int tid  = threadIdx.x;
    const int lane = tid & 63, wid = tid >> 6;
    const int b    = blockIdx.x;
    if (tid < 16)       { b0s[tid] = b0[tid]; w1s[tid] = W1[tid]; }
    if (tid < BK_NODES) hist[tid] = 0;
    __syncthreads();

    const int   ecnt = min(cursorF[b * CUR_STRIDE], BCAPF);
    const int2* eb   = ebinF + (size_t)b * BCAPF;
    for (int i = tid; i < ecnt; i += 512) {
        int2 e = eb[i];
        stage[i] = e;
        atomicAdd(&hist[e.y >> 17], 1);
    }
    __syncthreads();

    if (tid < BK_NODES) scn[tid] = hist[tid];
    __syncthreads();
    for (int off = 1; off < BK_NODES; off <<= 1) {
        int v = 0;
        if (tid < BK_NODES && tid >= off) v = scn[tid - off];
        __syncthreads();
        if (tid < BK_NODES && tid >= off) scn[tid] += v;
        __syncthreads();
    }
    if (tid < BK_NODES) { int e = scn[tid] - hist[tid]; scn[tid] = e; run[tid] = 0; }
    __syncthreads();

    for (int i = tid; i < ecnt; i += 512) {
        int dl = stage[i].y >> 17;
        int r  = atomicAdd(&run[dl], 1);
        idx[scn[dl] + r] = (unsigned short)i;
    }
    __syncthreads();

    for (int n = wid; n < BK_NODES; n += 8) {
        const int v = b * BK_NODES + n;
        if (v >= N_NODES) continue;
        const int beg = scn[n], dv = hist[n];
        const int f2  = lane & 7;
        const int g   = lane >> 3;
        float acc0 = 0.f, acc1 = 0.f;
        for (int j = g; j < dv; j += 16) {
            int2 e0 = stage[idx[beg + j]];
            int  j1 = j + 8;
            int2 e1 = (j1 < dv) ? stage[idx[beg + j1]] : stage[0];
            if (j1 >= dv) e1.x = 0;
            unsigned u0 = *(const unsigned*)(z0b + (size_t)(e0.y & 0x1FFFF) * F_HID + f2 * 2);
            unsigned u1 = *(const unsigned*)(z0b + (size_t)(e1.y & 0x1FFFF) * F_HID + f2 * 2);
            float w0 = __int_as_float(e0.x), w1 = __int_as_float(e1.x);
            acc0 = fmaf(__uint_as_float(u0 << 16),         w0, acc0);
            acc1 = fmaf(__uint_as_float(u0 & 0xFFFF0000u), w0, acc1);
            acc0 = fmaf(__uint_as_float(u1 << 16),         w1, acc0);
            acc1 = fmaf(__uint_as_float(u1 & 0xFFFF0000u), w1, acc1);
        }
        acc0 += __shfl_xor(acc0, 8);  acc1 += __shfl_xor(acc1, 8);
        acc0 += __shfl_xor(acc0, 16); acc1 += __shfl_xor(acc1, 16);
        acc0 += __shfl_xor(acc0, 32); acc1 += __shfl_xor(acc1, 32);
        float cc = fmaxf(acc0 + b0s[f2 * 2], 0.f) * w1s[f2 * 2]
                 + fmaxf(acc1 + b0s[f2 * 2 + 1], 0.f) * w1s[f2 * 2 + 1];
        cc += __shfl_xor(cc, 1);
        cc += __shfl_xor(cc, 2);
        cc += __shfl_xor(cc, 4);
        if (lane == 0) z1[v] = cc;
    }
}

// ---------------------------------------------------------------------------
// K4: layer 1 from bucket-grouped ebinF: 1 LDS atomic/edge + fused sigmoid.
// ---------------------------------------------------------------------------
__global__ __launch_bounds__(256) void k_g1(const int* __restrict__ cursorF,
                                            const int2* __restrict__ ebinF,
                                            const float* __restrict__ z1,
                                            const float* __restrict__ b1,
                                            float* __restrict__ out) {
    __shared__ float acc[BK_NODES];
    const int tid = threadIdx.x;
    const int b   = blockIdx.x;
    if (tid < BK_NODES) acc[tid] = 0.f;
    __syncthreads();
    const int   ecnt = min(cursorF[b * CUR_STRIDE], BCAPF);
    const int2* eb   = ebinF + (size_t)b * BCAPF;
    for (int i = tid; i < ecnt; i += 512) {
        int2 e0 = eb[i];
        int  i1 = i + 256;
        int2 e1 = (i1 < ecnt) ? eb[i1] : make_int2(0, 0);
        float m0 = z1[e0.y & 0x1FFFF] * __int_as_float(e0.x);
        float m1 = z1[e1.y & 0x1FFFF] * __int_as_float(e1.x);
        atomicAdd(&acc[e0.y >> 17], m0);
        if (i1 < ecnt) atomicAdd(&acc[e1.y >> 17], m1);
    }
    __syncthreads();
    if (tid < BK_NODES) {
        int v = b * BK_NODES + tid;
        if (v < N_NODES) out[v] = 1.f / (1.f + expf(-(acc[tid] + b1[0])));
    }
}

extern "C" void kernel_launch(void* const* d_in, const int* in_sizes, int n_in,
                              void* d_out, int out_size, void* d_ws, size_t ws_size,
                              hipStream_t stream) {
    const float* x   = (const float*)d_in[0];
    const int*   src = (const int*)d_in[1];
    const int*   dst = (const int*)d_in[2];
    const float* ew  = (const float*)d_in[3];
    const float* W0  = (const float*)d_in[4];
    const float* b0  = (const float*)d_in[5];
    const float* W1  = (const float*)d_in[6];
    const float* b1  = (const float*)d_in[7];
    float* out = (float*)d_out;

    // Workspace (~61 MB): z0b | z1 | cursorC | cursorF | ebinC | ebinF
    unsigned short* z0b = (unsigned short*)d_ws;                 // 3.2 MB
    float* z1      = (float*)(z0b + (size_t)N_NODES * F_HID);    // 400 KB
    int*   cursorC = (int*)(z1 + N_NODES);                       // 98*64 B
    int*   cursorF = cursorC + NBC * CUR_STRIDE;                 // 782*64 B
    int2*  ebinC   = (int2*)(cursorF + NB * CUR_STRIDE);         // 27.3 MB
    int2*  ebinF   = ebinC + (size_t)NBC * BCAPC;                // 30.0 MB

    hipMemsetAsync(cursorC, 0,
                   (size_t)(NBC + NB) * CUR_STRIDE * sizeof(int), stream);

    k_bin1<<<(N_EDGES + CHUNK - 1) / CHUNK, BIN_T, 0, stream>>>(src, dst, ew,
                                                                cursorC, ebinC);
    k_xw0 <<<(N_NODES + 63) / 64, 256, 0, stream>>>(x, W0, z0b, N_NODES);
    k_bin2<<<NBC * CPB2, BIN_T, 0, stream>>>(cursorC, ebinC, cursorF, ebinF);
    k_sg0 <<<NB, 512, 0, stream>>>(cursorF, ebinF, z0b, b0, W1, z1);
    k_g1  <<<NB, 256, 0, stream>>>(cursorF, ebinF, z1, b1, out);
}

// Round 9
// 130.358 us; speedup vs baseline: 3.3965x; 1.1365x over previous
//
#include <hip/hip_runtime.h>

#define N_NODES 100000
#define N_EDGES 3200000
#define F_IN 128
#define F_HID 16

// fine buckets (consumer-facing)
#define BK_LG 7
#define BK_NODES 128
#define NB ((N_NODES + BK_NODES - 1) / BK_NODES)      // 782
#define BCAPF 4736                                    // avg 4093, +10 sigma; 4x/CU LDS fit
// coarse buckets (pass-1)
#define CLG 10
#define CNODES 1024
#define NBC ((N_NODES + CNODES - 1) / CNODES)         // 98
#define NBC_P 128
#define BCAPC 34816                                   // avg 32768, +11 sigma
#define CPB2 9                                        // pass-2 chunks per coarse
#define CHUNK2 4096
#define CHUNK1 2048                                   // pass-1 chunk (256 threads)
#define NCH1 ((N_EDGES + CHUNK1 - 1) / CHUNK1)        // 1563
#define NXB ((N_NODES + 63) / 64)                     // 1563 xw0 tiles
#define CUR_STRIDE 16

__device__ __forceinline__ unsigned short f2bf_rne(float f) {
    unsigned u = __float_as_uint(f);
    u += 0x7FFFu + ((u >> 16) & 1u);
    return (unsigned short)(u >> 16);
}

// ---------------------------------------------------------------------------
// K1 (fused producer): even blocks run an xw0 tile (z0=x@W0 -> bf16),
// odd blocks run a pass-1 bin chunk (coarse 1024-node buckets).
// Unioned smem: max(41216 xw0, ~21000 bin1) bytes.
// ---------------------------------------------------------------------------
__global__ __launch_bounds__(256) void k_pre(const float* __restrict__ x,
                                             const float* __restrict__ W0,
                                             unsigned short* __restrict__ z0b,
                                             const int* __restrict__ src,
                                             const int* __restrict__ dst,
                                             const float* __restrict__ ew,
                                             int* __restrict__ cursorC,
                                             int2* __restrict__ ebinC) {
    __shared__ __align__(16) char smem[41216];
    const int tid = threadIdx.x;

    if ((blockIdx.x & 1) == 0) {
        // ------------------- xw0 role -------------------
        const int xb = blockIdx.x >> 1;
        if (xb >= NXB) return;
        float* xs  = (float*)smem;                 // [64][129]
        float* w0s = (float*)(smem + 33024);       // [128*16]
        for (int i = tid; i < F_IN * F_HID; i += 256) w0s[i] = W0[i];
        const int row0 = xb * 64;
        for (int i = tid; i < 64 * (F_IN / 4); i += 256) {
            int r  = i / (F_IN / 4);
            int c4 = i % (F_IN / 4);
            float4 v = make_float4(0.f, 0.f, 0.f, 0.f);
            int row = row0 + r;
            if (row < N_NODES) v = ((const float4*)(x + (size_t)row * F_IN))[c4];
            xs[r * 129 + c4 * 4 + 0] = v.x; xs[r * 129 + c4 * 4 + 1] = v.y;
            xs[r * 129 + c4 * 4 + 2] = v.z; xs[r * 129 + c4 * 4 + 3] = v.w;
        }
        __syncthreads();
        const int r  = tid & 63;
        const int cg = tid >> 6;
        float a0 = 0.f, a1 = 0.f, a2 = 0.f, a3 = 0.f;
        #pragma unroll 8
        for (int k = 0; k < F_IN; ++k) {
            float xv = xs[r * 129 + k];
            a0 = fmaf(xv, w0s[k * F_HID + cg * 4 + 0], a0);
            a1 = fmaf(xv, w0s[k * F_HID + cg * 4 + 1], a1);
            a2 = fmaf(xv, w0s[k * F_HID + cg * 4 + 2], a2);
            a3 = fmaf(xv, w0s[k * F_HID + cg * 4 + 3], a3);
        }
        int row = row0 + r;
        if (row < N_NODES) {
            ushort4 p = make_ushort4(f2bf_rne(a0), f2bf_rne(a1),
                                     f2bf_rne(a2), f2bf_rne(a3));
            *(ushort4*)(z0b + (size_t)row * F_HID + cg * 4) = p;
        }
    } else {
        // ------------------- bin1 role -------------------
        const int ch = blockIdx.x >> 1;
        if (ch >= NCH1) return;
        int2* stage = (int2*)smem;                            // 2048*8 = 16384
        unsigned char* sbid = (unsigned char*)(smem + 16384); // 2048
        int* cnt  = (int*)(smem + 18432);
        int* excl = (int*)(smem + 18944);
        int* run  = (int*)(smem + 19456);
        int* gb   = (int*)(smem + 19968);
        int* alw  = (int*)(smem + 20480);
        int* wtot = (int*)(smem + 20992);
        const int e0  = ch * CHUNK1;
        const int nch = min(CHUNK1, N_EDGES - e0);

        for (int i = tid; i < NBC_P; i += 256) cnt[i] = 0;
        __syncthreads();

        const int EPT1 = CHUNK1 / 256;            // 8
        int es[8], eb[8], edl[8]; float ww[8];
        #pragma unroll
        for (int k = 0; k < EPT1; ++k) {
            int idx = k * 256 + tid;
            if (idx < nch) {
                int e = e0 + idx;
                int d = dst[e];
                es[k]  = src[e];
                ww[k]  = ew[e];
                eb[k]  = d >> CLG;
                edl[k] = d & (CNODES - 1);
                atomicAdd(&cnt[eb[k]], 1);
            } else {
                eb[k] = -1;
            }
        }
        __syncthreads();

        // exclusive scan of cnt[0..128) via 2-wave shuffle
        {
            const int lane = tid & 63;
            int inc = 0, dv_ = 0;
            if (tid < NBC_P) {
                dv_ = cnt[tid];
                inc = dv_;
                #pragma unroll
                for (int off = 1; off < 64; off <<= 1) {
                    int t = __shfl_up(inc, off);
                    if (lane >= off) inc += t;
                }
                if (lane == 63) wtot[tid >> 6] = inc;
            }
            __syncthreads();
            if (tid < NBC_P) {
                int base = (tid >= 64) ? wtot[0] : 0;
                excl[tid] = base + inc - dv_;
            }
        }
        __syncthreads();

        if (tid < NBC) {
            int c = cnt[tid];
            if (c > 0) {
                int old = atomicAdd(&cursorC[tid * CUR_STRIDE], c);
                int a = BCAPC - old;
                a = (a < 0) ? 0 : ((a > c) ? c : a);
                alw[tid] = a;
                gb[tid]  = tid * BCAPC + old;
            } else {
                alw[tid] = 0;
                gb[tid]  = tid * BCAPC;
            }
            run[tid] = 0;
        }
        __syncthreads();

        #pragma unroll
        for (int k = 0; k < EPT1; ++k) {
            if (eb[k] >= 0) {
                int b = eb[k];
                int p = excl[b] + atomicAdd(&run[b], 1);
                stage[p] = make_int2(__float_as_int(ww[k]), es[k] | (edl[k] << 17));
                sbid[p]  = (unsigned char)b;
            }
        }
        __syncthreads();

        for (int s = tid; s < nch; s += 256) {
            int b   = sbid[s];
            int off = s - excl[b];
            if (off < alw[b]) ebinC[(size_t)gb[b] + off] = stage[s];
        }
    }
}

// ---------------------------------------------------------------------------
// K2: pass-2 split coarse->fine (8-way) + per-node degree histogram
// (LDS dcnt[1024] -> striped global atomics into deg[]).
// ---------------------------------------------------------------------------
__global__ __launch_bounds__(512) void k_bin2(const int* __restrict__ cursorC,
                                              const int2* __restrict__ ebinC,
                                              int* __restrict__ cursorF,
                                              int2* __restrict__ ebinF,
                                              int* __restrict__ deg) {
    __shared__ int cntw[64], runw[64], base[64];
    __shared__ int totals[8], excl_s[8], gb8[8], alw8[8];
    __shared__ int dcnt[CNODES];
    __shared__ int2 stage[CHUNK2];
    __shared__ unsigned char sbid[CHUNK2];
    const int tid = threadIdx.x;
    const int wid = tid >> 6;
    const int c   = blockIdx.x / CPB2;
    const int ck  = blockIdx.x % CPB2;
    const int ecnt = min(cursorC[c * CUR_STRIDE], BCAPC);
    const int beg  = ck * CHUNK2;
    const int n2   = min(CHUNK2, ecnt - beg);
    if (n2 <= 0) return;
    const int2* eC = ebinC + (size_t)c * BCAPC + beg;

    if (tid < 64) { cntw[tid] = 0; runw[tid] = 0; }
    for (int i = tid; i < CNODES; i += 512) dcnt[i] = 0;
    __syncthreads();

    const int EPT2 = CHUNK2 / 512;               // 8
    int fid[8]; int2 pk[8];
    #pragma unroll
    for (int k = 0; k < EPT2; ++k) {
        int idx = k * 512 + tid;
        if (idx < n2) {
            int2 e = eC[idx];
            int dlc = e.y >> 17;
            int f   = dlc >> BK_LG;
            fid[k]  = f;
            pk[k]   = make_int2(e.x, (e.y & 0x1FFFF) | ((dlc & (BK_NODES - 1)) << 17));
            atomicAdd(&cntw[f * 8 + wid], 1);
            atomicAdd(&dcnt[dlc], 1);
        } else {
            fid[k] = -1;
        }
    }
    __syncthreads();

    if (tid < 8) {
        int t = 0;
        #pragma unroll
        for (int w = 0; w < 8; ++w) t += cntw[tid * 8 + w];
        totals[tid] = t;
    }
    __syncthreads();
    if (tid < 8) {
        int e = 0;
        for (int f = 0; f < 8; ++f) if (f < tid) e += totals[f];
        excl_s[tid] = e;
        int t = totals[tid];
        int fb = c * 8 + tid;
        if (t > 0 && fb < NB) {
            int old = atomicAdd(&cursorF[fb * CUR_STRIDE], t);
            int a = BCAPF - old;
            a = (a < 0) ? 0 : ((a > t) ? t : a);
            alw8[tid] = a;
            gb8[tid]  = fb * BCAPF + old;
        } else {
            alw8[tid] = 0;
            gb8[tid]  = 0;
        }
    }
    __syncthreads();
    if (tid < 64) {
        int f = tid >> 3, w = tid & 7;
        int bb = excl_s[f];
        for (int w2 = 0; w2 < 8; ++w2) if (w2 < w) bb += cntw[f * 8 + w2];
        base[tid] = bb;
    }
    __syncthreads();

    #pragma unroll
    for (int k = 0; k < EPT2; ++k) {
        if (fid[k] >= 0) {
            int slot = fid[k] * 8 + wid;
            int p = base[slot] + atomicAdd(&runw[slot], 1);
            stage[p] = pk[k];
            sbid[p]  = (unsigned char)fid[k];
        }
    }
    __syncthreads();

    for (int s = tid; s < n2; s += 512) {
        int f   = sbid[s];
        int off = s - excl_s[f];
        if (off < alw8[f]) ebinF[(size_t)gb8[f] + off] = stage[s];
    }

    // flush per-node degree counts (striped over 400KB, ~1K atomics/block)
    for (int i = tid; i < CNODES; i += 512) {
        int d = dcnt[i];
        int v = c * CNODES + i;
        if (d > 0 && v < N_NODES) atomicAdd(&deg[v], d);
    }
}

// ---------------------------------------------------------------------------
// K3: gather layer 0 with DIRECT-PLACE sort (deg precomputed by k_bin2):
// 2-wave shuffle scan of deg -> stage edges straight into sorted LDS slots
// -> per-node register gather + fused relu/b0/W1-dot.
// ---------------------------------------------------------------------------
__global__ __launch_bounds__(512) void k_sg0(const int* __restrict__ deg,
                                             const int2* __restrict__ ebinF,
                                             const unsigned short* __restrict__ z0b,
                                             const float* __restrict__ b0,
                                             const float* __restrict__ W1,
                                             float* __restrict__ z1) {
    __shared__ int2 sorted[BCAPF];               // 37.9 KB
    __shared__ int scn[BK_NODES], dg[BK_NODES], run[BK_NODES];
    __shared__ int wtot[2], ecnt_s;
    __shared__ float b0s[16], w1s[16];
    const int tid  = threadIdx.x;
    const int lane = tid & 63, wid = tid >> 6;
    const int b    = blockIdx.x;
    if (tid < 16) { b0s[tid] = b0[tid]; w1s[tid] = W1[tid]; }

    // exclusive scan of this bucket's 128 degrees (waves 0-1)
    int inc = 0, d_ = 0;
    if (tid < BK_NODES) {
        int v = b * BK_NODES + tid;
        d_ = (v < N_NODES) ? deg[v] : 0;
        dg[tid]  = d_;
        run[tid] = 0;
        inc = d_;
        #pragma unroll
        for (int off = 1; off < 64; off <<= 1) {
            int t = __shfl_up(inc, off);
            if (lane >= off) inc += t;
        }
        if (lane == 63) wtot[tid >> 6] = inc;
    }
    __syncthreads();
    if (tid < BK_NODES) {
        int base = (tid >= 64) ? wtot[0] : 0;
        scn[tid] = base + inc - d_;
        if (tid == BK_NODES - 1) ecnt_s = min(base + inc, BCAPF);
    }
    __syncthreads();

    // stage directly into sorted position (1 LDS atomic + 1 write per edge)
    const int ecnt = ecnt_s;
    const int2* eb = ebinF + (size_t)b * BCAPF;
    for (int i = tid; i < ecnt; i += 512) {
        int2 e  = eb[i];
        int  dl = e.y >> 17;
        int  p  = scn[dl] + atomicAdd(&run[dl], 1);
        if (p < BCAPF) sorted[p] = e;
    }
    __syncthreads();

    // gather: wave w handles local nodes w, w+8, ...
    for (int n = wid; n < BK_NODES; n += 8) {
        const int v = b * BK_NODES + n;
        if (v >= N_NODES) continue;
        const int beg = scn[n];
        const int end = min(beg + dg[n], BCAPF);
        const int dv  = end - beg;
        const int f2  = lane & 7;
        const int g   = lane >> 3;
        float acc0 = 0.f, acc1 = 0.f;
        for (int j = g; j < dv; j += 16) {
            int2 e0 = sorted[beg + j];
            int  j1 = j + 8;
            int2 e1 = (j1 < dv) ? sorted[beg + j1] : make_int2(0, 0);
            unsigned u0 = *(const unsigned*)(z0b + (size_t)(e0.y & 0x1FFFF) * F_HID + f2 * 2);
            unsigned u1 = *(const unsigned*)(z0b + (size_t)(e1.y & 0x1FFFF) * F_HID + f2 * 2);
            float w0 = __int_as_float(e0.x), w1 = __int_as_float(e1.x);
            acc0 = fmaf(__uint_as_float(u0 << 16),         w0, acc0);
            acc1 = fmaf(__uint_as_float(u0 & 0xFFFF0000u), w0, acc1);
            acc0 = fmaf(__uint_as_float(u1 << 16),         w1, acc0);
            acc1 = fmaf(__uint_as_float(u1 & 0xFFFF0000u), w1, acc1);
        }
        acc0 += __shfl_xor(acc0, 8);  acc1 += __shfl_xor(acc1, 8);
        acc0 += __shfl_xor(acc0, 16); acc1 += __shfl_xor(acc1, 16);
        acc0 += __shfl_xor(acc0, 32); acc1 += __shfl_xor(acc1, 32);
        float cc = fmaxf(acc0 + b0s[f2 * 2], 0.f) * w1s[f2 * 2]
                 + fmaxf(acc1 + b0s[f2 * 2 + 1], 0.f) * w1s[f2 * 2 + 1];
        cc += __shfl_xor(cc, 1);
        cc += __shfl_xor(cc, 2);
        cc += __shfl_xor(cc, 4);
        if (lane == 0) z1[v] = cc;
    }
}

// ---------------------------------------------------------------------------
// K4: layer 1 from bucket-grouped ebinF: 1 LDS atomic/edge + fused sigmoid.
// ---------------------------------------------------------------------------
__global__ __launch_bounds__(256) void k_g1(const int* __restrict__ cursorF,
                                            const int2* __restrict__ ebinF,
                                            const float* __restrict__ z1,
                                            const float* __restrict__ b1,
                                            float* __restrict__ out) {
    __shared__ float acc[BK_NODES];
    const int tid = threadIdx.x;
    const int b   = blockIdx.x;
    if (tid < BK_NODES) acc[tid] = 0.f;
    __syncthreads();
    const int   ecnt = min(cursorF[b * CUR_STRIDE], BCAPF);
    const int2* eb   = ebinF + (size_t)b * BCAPF;
    for (int i = tid; i < ecnt; i += 512) {
        int2 e0 = eb[i];
        int  i1 = i + 256;
        int2 e1 = (i1 < ecnt) ? eb[i1] : make_int2(0, 0);
        float m0 = z1[e0.y & 0x1FFFF] * __int_as_float(e0.x);
        float m1 = z1[e1.y & 0x1FFFF] * __int_as_float(e1.x);
        atomicAdd(&acc[e0.y >> 17], m0);
        if (i1 < ecnt) atomicAdd(&acc[e1.y >> 17], m1);
    }
    __syncthreads();
    if (tid < BK_NODES) {
        int v = b * BK_NODES + tid;
        if (v < N_NODES) out[v] = 1.f / (1.f + expf(-(acc[tid] + b1[0])));
    }
}

extern "C" void kernel_launch(void* const* d_in, const int* in_sizes, int n_in,
                              void* d_out, int out_size, void* d_ws, size_t ws_size,
                              hipStream_t stream) {
    const float* x   = (const float*)d_in[0];
    const int*   src = (const int*)d_in[1];
    const int*   dst = (const int*)d_in[2];
    const float* ew  = (const float*)d_in[3];
    const float* W0  = (const float*)d_in[4];
    const float* b0  = (const float*)d_in[5];
    const float* W1  = (const float*)d_in[6];
    const float* b1  = (const float*)d_in[7];
    float* out = (float*)d_out;

    // Workspace (~61 MB): z0b | z1 | deg | cursorC | cursorF | ebinC | ebinF
    unsigned short* z0b = (unsigned short*)d_ws;                 // 3.2 MB
    float* z1      = (float*)(z0b + (size_t)N_NODES * F_HID);    // 400 KB
    int*   deg     = (int*)(z1 + N_NODES);                       // 400 KB
    int*   cursorC = deg + N_NODES;                              // 6.3 KB
    int*   cursorF = cursorC + NBC * CUR_STRIDE;                 // 50 KB
    int2*  ebinC   = (int2*)(cursorF + NB * CUR_STRIDE);         // 27.3 MB
    int2*  ebinF   = ebinC + (size_t)NBC * BCAPC;                // 29.6 MB

    // zero deg + both cursor arrays in one contiguous memset
    hipMemsetAsync(deg, 0,
                   ((size_t)N_NODES + (size_t)(NBC + NB) * CUR_STRIDE) * sizeof(int),
                   stream);

    k_pre <<<2 * NCH1, 256, 0, stream>>>(x, W0, z0b, src, dst, ew, cursorC, ebinC);
    k_bin2<<<NBC * CPB2, 512, 0, stream>>>(cursorC, ebinC, cursorF, ebinF, deg);
    k_sg0 <<<NB, 512, 0, stream>>>(deg, ebinF, z0b, b0, W1, z1);
    k_g1  <<<NB, 256, 0, stream>>>(cursorF, ebinF, z1, b1, out);
}